// Round 7
// baseline (2783.853 us; speedup 1.0000x reference)
//
#include <hip/hip_runtime.h>
#include <math.h>

// Residual VQ: x (262144,128) fp32, codebooks (3,256,128) fp32.
// Output: [indices as float (262144*3)] ++ [quantized (262144*128)].
//
// ARITHMETIC CONTRACT (absmax=0 — do not change):
//   M_k  = OpenBLAS sgemm K-loop: sequential FMA chain j=0..127, acc init 0
//   A    = np.sum(r*r): pairwise_sum 8-accumulator scheme, products rounded
//          separately (fmaf(x,x,0) = single-rounded product, blocks fusion)
//   d2_k = (A - 2.0f*M_k) + B_k ; argmin strict < ascending k
//          (fmaf(-2,M,A)+B == (A-2.0f*M)+B bit-exact: 2*M exact, one rounding)
//   residual: r1 = x - q0 (1 rounding), r2 = r1 - q1 (1 rounding) — in-place
//          LDS subtract, elementwise fp32, ref order
//   quantized = (q0 + q1) + q2 elementwise fp32, ref order
//
// ROUND 11 CHANGE: r10 still shows VALU issue ~2.7x the 327us FMA floor plus
// ~500us of stall. Remaining suspect: the codebook rides the SCALAR pipe —
// (a) 256 codebook floats/jc-iter vs ~112 SGPRs forces s_load batch juggling,
// (b) s_load and ds_read SHARE lgkmcnt, so every wait serializes the codebook
// fetch against the residual LDS reads (no overlap domains), (c) 4 waves x
// 16KB disjoint slices thrash the ~16KB scalar K$. Fix: derive cbT through an
// OPAQUE VGPR ZERO (inline asm v_mov) so uniformity analysis fails and the
// codebook is fetched with per-lane global_load_dwordx4 (vmcnt domain, deep
// outstanding queue, L1/L2-served splat loads; codebook is 384KB = L2-hot).
// ds_read (lgkm) and codebook loads (vmcnt) now overlap; SGPR juggling gone.
// Load path does not affect bits: arithmetic identical to r10 (verified).

constexpr int kItems = 262144;
constexpr int kDim   = 128;
constexpr int kNcb   = 3;
constexpr int kK     = 256;
constexpr int kBlock = 256;
constexpr int kIPB   = 64;         // items per block (one per lane)
constexpr int kEPW   = 64;         // entries per wave
constexpr int TE     = 32;         // entries per sub-tile (named accumulators)
constexpr int NJC    = kDim / 8;   // 16 dim-chunks of 8
constexpr int RS     = 132;        // LDS residual row stride (floats), +4 pad

__device__ __forceinline__ float sq_rn(float x) {
    return __builtin_fmaf(x, x, 0.0f);
}

// numpy pairwise_sum, n=128: 8 accumulators, acc_j = v[j]+v[j+8]+...+v[j+120],
// combined ((r0+r1)+(r2+r3))+((r4+r5)+(r6+r7)).
template <typename F>
__device__ __forceinline__ float np_pairwise128(F term) {
    float r0 = term(0), r1 = term(1), r2 = term(2), r3 = term(3),
          r4 = term(4), r5 = term(5), r6 = term(6), r7 = term(7);
    #pragma unroll
    for (int i = 8; i < 128; i += 8) {
        r0 = r0 + term(i + 0); r1 = r1 + term(i + 1);
        r2 = r2 + term(i + 2); r3 = r3 + term(i + 3);
        r4 = r4 + term(i + 4); r5 = r5 + term(i + 5);
        r6 = r6 + term(i + 6); r7 = r7 + term(i + 7);
    }
    return ((r0 + r1) + (r2 + r3)) + ((r4 + r5) + (r6 + r7));
}

// ---------- pre-kernel: B_k = np.sum(cb*cb, axis=-1) into d_ws (768 floats)
__global__ void rvq_btable(const float* __restrict__ cb,
                           float* __restrict__ Bt)
{
    const int m = blockIdx.x * 256 + threadIdx.x;   // 3 blocks x 256 = 768
    const float* row = cb + (size_t)m * kDim;
    Bt[m] = np_pairwise128([&](int j) { return sq_rn(row[j]); });
}

#define X32(X) X(0) X(1) X(2) X(3) X(4) X(5) X(6) X(7) \
  X(8) X(9) X(10) X(11) X(12) X(13) X(14) X(15) \
  X(16) X(17) X(18) X(19) X(20) X(21) X(22) X(23) \
  X(24) X(25) X(26) X(27) X(28) X(29) X(30) X(31)

// 32 entries x 8 dims; cbT is per-lane (opaque-zero offset) -> codebook comes
// in as global_load_dwordx4 on the vmcnt domain. Per-entry FMA chain stays
// sequential in j (bit-exact sgemm order).
#define MROW(e) { \
    const float4* rp = (const float4*)(cbT + (size_t)(e) * kDim); \
    const float4 ca = rp[2*jc], cd = rp[2*jc+1]; \
    m##e = __builtin_fmaf(ra.x, ca.x, m##e); \
    m##e = __builtin_fmaf(ra.y, ca.y, m##e); \
    m##e = __builtin_fmaf(ra.z, ca.z, m##e); \
    m##e = __builtin_fmaf(ra.w, ca.w, m##e); \
    m##e = __builtin_fmaf(rb.x, cd.x, m##e); \
    m##e = __builtin_fmaf(rb.y, cd.y, m##e); \
    m##e = __builtin_fmaf(rb.z, cd.z, m##e); \
    m##e = __builtin_fmaf(rb.w, cd.w, m##e); }

__global__ __launch_bounds__(kBlock, 4) void rvq_kernel(
    const float* __restrict__ x,
    const float* __restrict__ cb,
    const float* __restrict__ Bt,
    float* __restrict__ out)
{
    __shared__ float s_r[kIPB * RS];      // residuals, padded rows
    __shared__ float s_bestv[kBlock];
    __shared__ int   s_besti[kBlock];

    const int t = threadIdx.x;

    // opaque zero in a VGPR: defeats uniformity analysis for codebook loads
    int vzero;
    asm volatile("v_mov_b32 %0, 0" : "=v"(vzero));

    // ---- stage r = x (exact copy), coalesced global reads
    const float4* xb4 = (const float4*)(x + (size_t)blockIdx.x * kIPB * kDim);
    #pragma unroll
    for (int k = 0; k < (kIPB * kDim / 4) / kBlock; ++k) {   // 8 iters
        const int f = k * kBlock + t;              // float4 index in block tile
        const float4 v = xb4[f];
        *(float4*)(s_r + (f >> 5) * RS + (f & 31) * 4) = v;
    }
    __syncthreads();

    const int wav  = __builtin_amdgcn_readfirstlane(t >> 6);
    const int lane = t & 63;
    const int item = blockIdx.x * kIPB + lane;
    const int gbase = wav * kEPW;
    const float* rrow = s_r + lane * RS;   // this lane's item row

    int sel0 = 0, sel1 = 0, sel2 = 0;

    #pragma unroll 1
    for (int c = 0; c < kNcb; ++c) {
        float A = 0.0f;
        float best = INFINITY;
        int bi = gbase;

        // ======== sub-tile 0: entries [gbase, gbase+32), A fused ========
        {
            const int kb = gbase;
            const float* cbT = cb + ((size_t)c * kK + kb) * kDim + vzero;

            #define MDECL(e) float m##e = 0.0f;
            X32(MDECL)
            #undef MDECL
            float a0 = 0.f, a1 = 0.f, a2 = 0.f, a3 = 0.f,
                  a4 = 0.f, a5 = 0.f, a6 = 0.f, a7 = 0.f;

            #pragma unroll 1
            for (int jc = 0; jc < NJC; ++jc) {
                const float4 ra = *(const float4*)(rrow + jc * 8);
                const float4 rb = *(const float4*)(rrow + jc * 8 + 4);

                // A: numpy 8-stripe, j-ascending per stripe
                a0 = a0 + sq_rn(ra.x); a1 = a1 + sq_rn(ra.y);
                a2 = a2 + sq_rn(ra.z); a3 = a3 + sq_rn(ra.w);
                a4 = a4 + sq_rn(rb.x); a5 = a5 + sq_rn(rb.y);
                a6 = a6 + sq_rn(rb.z); a7 = a7 + sq_rn(rb.w);

                X32(MROW)
            }

            A = ((a0 + a1) + (a2 + a3)) + ((a4 + a5) + (a6 + a7));

            // epilogue (ascending entries, strict <)
            #define EPI(e) { \
                float tt = __builtin_fmaf(-2.0f, m##e, A) + Bt[c * kK + kb + (e)]; \
                if (tt < best) { best = tt; bi = kb + (e); } }
            X32(EPI)
            #undef EPI
        }

        // ======== sub-tile 1: entries [gbase+32, gbase+64) ========
        {
            const int kb = gbase + TE;
            const float* cbT = cb + ((size_t)c * kK + kb) * kDim + vzero;

            #define MDECL(e) float m##e = 0.0f;
            X32(MDECL)
            #undef MDECL

            #pragma unroll 1
            for (int jc = 0; jc < NJC; ++jc) {
                const float4 ra = *(const float4*)(rrow + jc * 8);
                const float4 rb = *(const float4*)(rrow + jc * 8 + 4);
                X32(MROW)
            }

            #define EPI(e) { \
                float tt = __builtin_fmaf(-2.0f, m##e, A) + Bt[c * kK + kb + (e)]; \
                if (tt < best) { best = tt; bi = kb + (e); } }
            X32(EPI)
            #undef EPI
        }

        // ---- cross-wave argmin, ascending group order == numpy first-min
        s_bestv[t] = best;
        s_besti[t] = bi;
        __syncthreads();
        float bv = s_bestv[lane];
        int   bx = s_besti[lane];
        #pragma unroll
        for (int g = 1; g < kBlock / 64; ++g) {
            const float v  = s_bestv[g * 64 + lane];
            const int   ix = s_besti[g * 64 + lane];
            if (v < bv) { bv = v; bx = ix; }
        }
        if (c == 0) sel0 = bx; else if (c == 1) sel1 = bx; else sel2 = bx;

        // ---- in-place residual update (skip after last codebook)
        if (c < 2) {
            const int sel = (c == 0) ? sel0 : sel1;     // valid for item t&63
            const int it  = t & 63;
            const int qtr = t >> 6;
            const float4* cw4 =
                (const float4*)(cb + ((size_t)c * kK + sel) * kDim);
            #pragma unroll
            for (int i2 = 0; i2 < 8; ++i2) {
                const int c16 = qtr * 8 + i2;
                const float4 w = cw4[c16];
                float4 rv = *(float4*)(s_r + it * RS + c16 * 4);
                rv.x = rv.x - w.x;  rv.y = rv.y - w.y;   // one rounding each,
                rv.z = rv.z - w.z;  rv.w = rv.w - w.w;   // ref order
                *(float4*)(s_r + it * RS + c16 * 4) = rv;
            }
            __syncthreads();   // r ready for next c; also gates s_bestv reuse
        }
    }

    // ---- outputs
    float* out_idx = out;                             // (items, 3) as float
    float* out_q   = out + (size_t)kItems * kNcb;     // (items, 128)
    if (wav == 0) {
        out_idx[(size_t)item * kNcb + 0] = (float)sel0;
        out_idx[(size_t)item * kNcb + 1] = (float)sel1;
        out_idx[(size_t)item * kNcb + 2] = (float)sel2;
    }
    // quantized: thread t writes quarter (t>>6) of item (t&63)
    {
        const int it  = t & 63;
        const int qtr = t >> 6;
        const int oitem = blockIdx.x * kIPB + it;
        const float4* q0v = (const float4*)(cb + ((size_t)0 * kK + sel0) * kDim);
        const float4* q1v = (const float4*)(cb + ((size_t)1 * kK + sel1) * kDim);
        const float4* q2v = (const float4*)(cb + ((size_t)2 * kK + sel2) * kDim);
        float4* qov = (float4*)(out_q + (size_t)oitem * kDim);
        #pragma unroll
        for (int i2 = 0; i2 < 8; ++i2) {
            const int c16 = qtr * 8 + i2;
            const float4 u = q0v[c16], v = q1v[c16], w = q2v[c16];
            float4 o;
            o.x = (u.x + v.x) + w.x;
            o.y = (u.y + v.y) + w.y;
            o.z = (u.z + v.z) + w.z;
            o.w = (u.w + v.w) + w.w;
            qov[c16] = o;   // ((0+q0)+q1)+q2 in fp32, ref order
        }
    }
}

extern "C" void kernel_launch(void* const* d_in, const int* in_sizes, int n_in,
                              void* d_out, int out_size, void* d_ws, size_t ws_size,
                              hipStream_t stream) {
    const float* x  = (const float*)d_in[0];
    const float* cb = (const float*)d_in[1];
    float* out = (float*)d_out;
    float* Bt  = (float*)d_ws;     // 768 floats
    rvq_btable<<<kNcb, 256, 0, stream>>>(cb, Bt);
    rvq_kernel<<<kItems / kIPB, kBlock, 0, stream>>>(x, cb, Bt, out);
}

// Round 8
// 1223.528 us; speedup vs baseline: 2.2753x; 2.2753x over previous
//
#include <hip/hip_runtime.h>
#include <math.h>

// Residual VQ: x (262144,128) fp32, codebooks (3,256,128) fp32.
// Output: [indices as float (262144*3)] ++ [quantized (262144*128)].
//
// ARITHMETIC CONTRACT (absmax=0 — do not change):
//   M_k  = OpenBLAS sgemm K-loop: sequential FMA chain j=0..127, acc init 0
//   A    = np.sum(r*r): pairwise_sum 8-accumulator scheme, products rounded
//          separately (fmaf(x,x,0) = single-rounded product, blocks fusion)
//   d2_k = (A - 2.0f*M_k) + B_k ; argmin strict < ascending k
//          (fmaf(-2,M,A)+B == (A-2.0f*M)+B bit-exact: 2*M exact, one rounding)
//   residual: r1 = x - q0 (1 rounding), r2 = r1 - q1 (1 rounding) — in-place
//          subtract in the global scratch, elementwise fp32, ref order
//   quantized = (q0 + q1) + q2 elementwise fp32, ref order
//
// ROUND 12 CHANGE: r11 refuted per-lane codebook loads (3030us, vmcnt/L1
// swamped) — codebook stays on the scalar pipe. r10's residual, however,
// lives in LDS: the hot loop is then the only code with BOTH s_load and
// ds_read in flight, and they SHARE lgkmcnt with out-of-order completion
// across queues -> compiler must conservatively drain lgkmcnt before each
// FMA group, serializing every jc iteration on SMEM latency (r10: 895us VALU
// busy + ~500us stall vs 350us floor). r6's loop — same MROW, same scalar
// codebook — but residual operands on the VMCNT domain ran at 1.37x floor.
// Fix: residual moves to a GLOBAL per-lane scratch = the out_q region itself
// (block-exclusive rows). cb0 reads x directly; after sel0 the update writes
// r1 into out_q; cb1 reads out_q, updates in place to r2; cb2 reads r2; the
// final quantized write overwrites the scratch after the last combine
// barrier (all r2 reads precede it). Block residual slice = 32KB = exactly
// L1, exclusively (codebook rides the scalar K$). L1 is write-through with
// invalidate-on-write-hit and __syncthreads drains vmcnt -> cross-wave
// visibility via L2 is sound. Bit-flow identical to r10 (verified absmax=0);
// only the storage location of r changes. LDS: 35KB -> 2KB.

constexpr int kItems = 262144;
constexpr int kDim   = 128;
constexpr int kNcb   = 3;
constexpr int kK     = 256;
constexpr int kBlock = 256;
constexpr int kIPB   = 64;         // items per block (one per lane)
constexpr int kEPW   = 64;         // entries per wave
constexpr int TE     = 32;         // entries per sub-tile (named accumulators)
constexpr int NJC    = kDim / 8;   // 16 dim-chunks of 8

__device__ __forceinline__ float sq_rn(float x) {
    return __builtin_fmaf(x, x, 0.0f);
}

// numpy pairwise_sum, n=128: 8 accumulators, acc_j = v[j]+v[j+8]+...+v[j+120],
// combined ((r0+r1)+(r2+r3))+((r4+r5)+(r6+r7)).
template <typename F>
__device__ __forceinline__ float np_pairwise128(F term) {
    float r0 = term(0), r1 = term(1), r2 = term(2), r3 = term(3),
          r4 = term(4), r5 = term(5), r6 = term(6), r7 = term(7);
    #pragma unroll
    for (int i = 8; i < 128; i += 8) {
        r0 = r0 + term(i + 0); r1 = r1 + term(i + 1);
        r2 = r2 + term(i + 2); r3 = r3 + term(i + 3);
        r4 = r4 + term(i + 4); r5 = r5 + term(i + 5);
        r6 = r6 + term(i + 6); r7 = r7 + term(i + 7);
    }
    return ((r0 + r1) + (r2 + r3)) + ((r4 + r5) + (r6 + r7));
}

// ---------- pre-kernel: B_k = np.sum(cb*cb, axis=-1) into d_ws (768 floats)
__global__ void rvq_btable(const float* __restrict__ cb,
                           float* __restrict__ Bt)
{
    const int m = blockIdx.x * 256 + threadIdx.x;   // 3 blocks x 256 = 768
    const float* row = cb + (size_t)m * kDim;
    Bt[m] = np_pairwise128([&](int j) { return sq_rn(row[j]); });
}

#define X32(X) X(0) X(1) X(2) X(3) X(4) X(5) X(6) X(7) \
  X(8) X(9) X(10) X(11) X(12) X(13) X(14) X(15) \
  X(16) X(17) X(18) X(19) X(20) X(21) X(22) X(23) \
  X(24) X(25) X(26) X(27) X(28) X(29) X(30) X(31)

// 32 entries x 8 dims; typed float4 uniform loads (merged s_load path),
// per-entry chain stays sequential in j
#define MROW(e) { \
    const float4* rp = (const float4*)(cbT + (size_t)(e) * kDim); \
    const float4 ca = rp[2*jc], cd = rp[2*jc+1]; \
    m##e = __builtin_fmaf(ra.x, ca.x, m##e); \
    m##e = __builtin_fmaf(ra.y, ca.y, m##e); \
    m##e = __builtin_fmaf(ra.z, ca.z, m##e); \
    m##e = __builtin_fmaf(ra.w, ca.w, m##e); \
    m##e = __builtin_fmaf(rb.x, cd.x, m##e); \
    m##e = __builtin_fmaf(rb.y, cd.y, m##e); \
    m##e = __builtin_fmaf(rb.z, cd.z, m##e); \
    m##e = __builtin_fmaf(rb.w, cd.w, m##e); }

__global__ __launch_bounds__(kBlock, 4) void rvq_kernel(
    const float* __restrict__ x,
    const float* __restrict__ cb,
    const float* __restrict__ Bt,
    float* __restrict__ out)
{
    __shared__ float s_bestv[kBlock];
    __shared__ int   s_besti[kBlock];

    const int t = threadIdx.x;

    // wave id PROVABLY uniform so codebook addrs become s_loads
    const int wav  = __builtin_amdgcn_readfirstlane(t >> 6);
    const int lane = t & 63;
    const int item = blockIdx.x * kIPB + lane;
    const int gbase = wav * kEPW;

    float* out_idx = out;                             // (items, 3) as float
    float* out_q   = out + (size_t)kItems * kNcb;     // (items, 128)

    const float* xrow = x + (size_t)item * kDim;          // cb0 residual
    const float* qrow = out_q + (size_t)item * kDim;      // cb1/2 residual

    int sel0 = 0, sel1 = 0, sel2 = 0;

    #pragma unroll 1
    for (int c = 0; c < kNcb; ++c) {
        // residual source for this codebook: x (c==0) or the scratch (c>=1)
        const float* rrow = (c == 0) ? xrow : qrow;

        float A = 0.0f;
        float best = INFINITY;
        int bi = gbase;

        // ======== sub-tile 0: entries [gbase, gbase+32), A fused ========
        {
            const int kb = gbase;
            const float* cbT = cb + ((size_t)c * kK + kb) * kDim;

            #define MDECL(e) float m##e = 0.0f;
            X32(MDECL)
            #undef MDECL
            float a0 = 0.f, a1 = 0.f, a2 = 0.f, a3 = 0.f,
                  a4 = 0.f, a5 = 0.f, a6 = 0.f, a7 = 0.f;

            #pragma unroll 1
            for (int jc = 0; jc < NJC; ++jc) {
                const float4 ra = *(const float4*)(rrow + jc * 8);
                const float4 rb = *(const float4*)(rrow + jc * 8 + 4);

                // A: numpy 8-stripe, j-ascending per stripe
                a0 = a0 + sq_rn(ra.x); a1 = a1 + sq_rn(ra.y);
                a2 = a2 + sq_rn(ra.z); a3 = a3 + sq_rn(ra.w);
                a4 = a4 + sq_rn(rb.x); a5 = a5 + sq_rn(rb.y);
                a6 = a6 + sq_rn(rb.z); a7 = a7 + sq_rn(rb.w);

                X32(MROW)
            }

            A = ((a0 + a1) + (a2 + a3)) + ((a4 + a5) + (a6 + a7));

            // epilogue (ascending entries, strict <)
            #define EPI(e) { \
                float tt = __builtin_fmaf(-2.0f, m##e, A) + Bt[c * kK + kb + (e)]; \
                if (tt < best) { best = tt; bi = kb + (e); } }
            X32(EPI)
            #undef EPI
        }

        // ======== sub-tile 1: entries [gbase+32, gbase+64) ========
        {
            const int kb = gbase + TE;
            const float* cbT = cb + ((size_t)c * kK + kb) * kDim;

            #define MDECL(e) float m##e = 0.0f;
            X32(MDECL)
            #undef MDECL

            #pragma unroll 1
            for (int jc = 0; jc < NJC; ++jc) {
                const float4 ra = *(const float4*)(rrow + jc * 8);
                const float4 rb = *(const float4*)(rrow + jc * 8 + 4);
                X32(MROW)
            }

            #define EPI(e) { \
                float tt = __builtin_fmaf(-2.0f, m##e, A) + Bt[c * kK + kb + (e)]; \
                if (tt < best) { best = tt; bi = kb + (e); } }
            X32(EPI)
            #undef EPI
        }

        // ---- cross-wave argmin, ascending group order == numpy first-min
        s_bestv[t] = best;
        s_besti[t] = bi;
        __syncthreads();
        float bv = s_bestv[lane];
        int   bx = s_besti[lane];
        #pragma unroll
        for (int g = 1; g < kBlock / 64; ++g) {
            const float v  = s_bestv[g * 64 + lane];
            const int   ix = s_besti[g * 64 + lane];
            if (v < bv) { bv = v; bx = ix; }
        }
        if (c == 0) sel0 = bx; else if (c == 1) sel1 = bx; else sel2 = bx;

        // ---- residual update into the out_q scratch (skip after last cb)
        // thread t updates quarter (t>>6) of item (t&63); same thread wrote
        // these addresses last round -> program order; cross-wave visibility
        // via the __syncthreads (vmcnt drained before s_barrier).
        if (c < 2) {
            const int sel = (c == 0) ? sel0 : sel1;     // valid for item t&63
            const int it  = t & 63;
            const int qtr = t >> 6;
            const size_t rowbase = (size_t)(blockIdx.x * kIPB + it) * kDim;
            const float* srow = (c == 0) ? (x + rowbase)
                                         : (const float*)(out_q + rowbase);
            float* drow = out_q + rowbase;
            const float4* cw4 =
                (const float4*)(cb + ((size_t)c * kK + sel) * kDim);
            #pragma unroll
            for (int i2 = 0; i2 < 8; ++i2) {
                const int c16 = qtr * 8 + i2;
                const float4 w = cw4[c16];
                float4 rv = *(const float4*)(srow + c16 * 4);
                rv.x = rv.x - w.x;  rv.y = rv.y - w.y;   // one rounding each,
                rv.z = rv.z - w.z;  rv.w = rv.w - w.w;   // ref order
                *(float4*)(drow + c16 * 4) = rv;
            }
            __syncthreads();   // r ready for next c; also gates s_bestv reuse
        }
    }

    // ---- outputs (all r2 scratch reads preceded the last combine barrier)
    if (wav == 0) {
        out_idx[(size_t)item * kNcb + 0] = (float)sel0;
        out_idx[(size_t)item * kNcb + 1] = (float)sel1;
        out_idx[(size_t)item * kNcb + 2] = (float)sel2;
    }
    // quantized: thread t writes quarter (t>>6) of item (t&63), overwriting
    // the residual scratch with the final values
    {
        const int it  = t & 63;
        const int qtr = t >> 6;
        const int oitem = blockIdx.x * kIPB + it;
        const float4* q0v = (const float4*)(cb + ((size_t)0 * kK + sel0) * kDim);
        const float4* q1v = (const float4*)(cb + ((size_t)1 * kK + sel1) * kDim);
        const float4* q2v = (const float4*)(cb + ((size_t)2 * kK + sel2) * kDim);
        float4* qov = (float4*)(out_q + (size_t)oitem * kDim);
        #pragma unroll
        for (int i2 = 0; i2 < 8; ++i2) {
            const int c16 = qtr * 8 + i2;
            const float4 u = q0v[c16], v = q1v[c16], w = q2v[c16];
            float4 o;
            o.x = (u.x + v.x) + w.x;
            o.y = (u.y + v.y) + w.y;
            o.z = (u.z + v.z) + w.z;
            o.w = (u.w + v.w) + w.w;
            qov[c16] = o;   // ((0+q0)+q1)+q2 in fp32, ref order
        }
    }
}

extern "C" void kernel_launch(void* const* d_in, const int* in_sizes, int n_in,
                              void* d_out, int out_size, void* d_ws, size_t ws_size,
                              hipStream_t stream) {
    const float* x  = (const float*)d_in[0];
    const float* cb = (const float*)d_in[1];
    float* out = (float*)d_out;
    float* Bt  = (float*)d_ws;     // 768 floats
    rvq_btable<<<kNcb, 256, 0, stream>>>(cb, Bt);
    rvq_kernel<<<kItems / kIPB, kBlock, 0, stream>>>(x, cb, Bt, out);
}